// Round 1
// baseline (418.424 us; speedup 1.0000x reference)
//
#include <hip/hip_runtime.h>
#include <hip/hip_bf16.h>
#include <math.h>

// cummax along axis 1 of [B=16, T=512, H=64, C=128] fp32.
// Flat index: ((b*T + t)*H + h)*C + c -> T-stride = H*C = 8192 floats.
// One thread per float2 column-pair; sequential running max over T.
// Memory-bound: 512 MiB total traffic -> ~85us floor at 6.3 TB/s.

#define T_DIM 512
#define HC 8192           // H*C floats per (b,t) slab
#define B_DIM 16

__global__ __launch_bounds__(128) void cummax_kernel(const float* __restrict__ in,
                                                     float* __restrict__ out) {
    // gid in [0, B*HC/2) = [0, 65536)
    int gid = blockIdx.x * blockDim.x + threadIdx.x;
    int b   = gid >> 12;          // / (HC/2 = 4096)
    int cp  = gid & 4095;         // float2-column within the batch slab

    const float2* __restrict__ src =
        (const float2*)(in  + (size_t)b * T_DIM * HC) + cp;
    float2* __restrict__ dst =
        (float2*)(out + (size_t)b * T_DIM * HC) + cp;

    float mx = -INFINITY;
    float my = -INFINITY;

    #pragma unroll 8
    for (int t = 0; t < T_DIM; ++t) {
        float2 v = src[t * (HC / 2)];
        mx = fmaxf(mx, v.x);
        my = fmaxf(my, v.y);
        float2 o;
        o.x = mx;
        o.y = my;
        dst[t * (HC / 2)] = o;
    }
}

extern "C" void kernel_launch(void* const* d_in, const int* in_sizes, int n_in,
                              void* d_out, int out_size, void* d_ws, size_t ws_size,
                              hipStream_t stream) {
    const float* in = (const float*)d_in[0];
    float* out = (float*)d_out;

    // 65536 threads total: 512 blocks x 128 threads -> 2 blocks/CU across 256 CUs.
    dim3 grid(512);
    dim3 block(128);
    cummax_kernel<<<grid, block, 0, stream>>>(in, out);
}